// Round 5
// baseline (4038.372 us; speedup 1.0000x reference)
//
#include <hip/hip_runtime.h>
#include <math.h>

typedef __attribute__((ext_vector_type(4))) float f32x4;
typedef __attribute__((ext_vector_type(4))) int   i32x4;
typedef __attribute__((ext_vector_type(8))) short bfrag8;   // 8 bf16 = 4 VGPRs

// ---- ws layout (bytes) ----
// wre_hi: 5 mats * 1024 * 256 * 2B = 2621440 @ 0
// wre_lo: same                              @ 2621440
#define WRE_LO_OFF 2621440
// hb (LLC domain): [parity(2)][layer(3)][256 rows][256 cols] bf16
#define HB_OFF     5242880   // 786432 B
// flags: FA (A-loads-done acks) and FF (iteration-complete), one uint per
// block, padded to 64 uints (256B). [bt(4)][layer(3)][nt(16)][64]
#define FA_OFF     6029312   // 49152 B
#define FF_OFF     6078464   // 49152 B
#define WS_END     6127616

// dynamic LDS: [2 mats][2 planes][64 rows][WROW bf16] = 135168 B (exact r0)
#define WROW 264
#define SMEM_BYTES (4 * 64 * WROW * 2)

__device__ __forceinline__ unsigned short f2bf(float f){
  union { float f; unsigned u; } x; x.f = f;
  unsigned r = x.u + 0x7FFFu + ((x.u >> 16) & 1u);   // RNE
  return (unsigned short)(r >> 16);
}
__device__ __forceinline__ float bf2f(unsigned short s){
  union { unsigned u; float f; } x; x.u = ((unsigned)s) << 16; return x.f;
}
__device__ __forceinline__ float sigf(float x){
  return 1.0f / (1.0f + __expf(-x));
}
__device__ __forceinline__ float tanh_fast(float x){
  x = fminf(fmaxf(x, -15.0f), 15.0f);
  float e = __expf(2.0f * x);
  return (e - 1.0f) / (e + 1.0f);
}

// ---- LLC-direct (device coherence point): sc0 sc1 bypasses L1 and L2.
// r0-proven scope for ALL cross-block communication.
__device__ __forceinline__ i32x4 llc_load_b128(const void* p){
  i32x4 r;
  asm volatile("global_load_dwordx4 %0, %1, off sc0 sc1"
               : "=v"(r) : "v"(p) : "memory");
  return r;
}
__device__ __forceinline__ void llc_store_b16(void* p, unsigned short v){
  unsigned int vv = v;
  asm volatile("global_store_short %0, %1, off sc0 sc1"
               : : "v"(p), "v"(vv) : "memory");
}
__device__ __forceinline__ void llc_store_u32(void* p, unsigned v){
  asm volatile("global_store_dword %0, %1, off sc0 sc1"
               : : "v"(p), "v"(v) : "memory");
}
__device__ __forceinline__ unsigned poll_llc(const unsigned int* p){
  unsigned r;
  asm volatile("global_load_dword %0, %1, off sc0 sc1\n\ts_waitcnt vmcnt(0)"
               : "=v"(r) : "v"(p) : "memory");
  return r;
}
__device__ __forceinline__ void wait_vm0(){
  asm volatile("s_waitcnt vmcnt(0)" ::: "memory");
}

// Reorder the 5 big weight mats into per-(nt)-contiguous rows, split bf16 hi/lo.
// dest row d in [0,1024): nt=d>>6, g=(d>>4)&3, n=d&15 ; src row = g*256 + nt*16 + n
__global__ void init_reorder(const float* __restrict__ hh0, const float* __restrict__ ih1,
                             const float* __restrict__ hh1, const float* __restrict__ ih2,
                             const float* __restrict__ hh2,
                             unsigned short* __restrict__ wre_hi,
                             unsigned short* __restrict__ wre_lo){
  int e = blockIdx.x * 256 + threadIdx.x;        // 5*2^18 total
  int mat = e >> 18;
  int d   = (e >> 8) & 1023;
  int k   = e & 255;
  int nt = d >> 6, g = (d >> 4) & 3, n = d & 15;
  int src_row = g*256 + nt*16 + n;
  const float* W = (mat==0) ? hh0 : (mat==1) ? ih1 : (mat==2) ? hh1 : (mat==3) ? ih2 : hh2;
  float v = W[src_row*256 + k];
  unsigned short hi = f2bf(v);
  float lo = v - bf2f(hi);
  wre_hi[e] = hi;
  wre_lo[e] = f2bf(lo);
}

__global__ void init_zero(uint4* __restrict__ p, int n16){
  int i = blockIdx.x * 256 + threadIdx.x;
  if (i < n16) p[i] = make_uint4(0u,0u,0u,0u);
}

// =====================================================================
// Layer-pipelined LSTM. 192 blocks = layer(3) x nt(16) x bt(4).
// MATH PATH: exact r0 (LDS-staged weights, identical MFMA order, identical
// cell update) -> bit-identical to the proven 3383us pass. Register-resident
// recurrent weights remain BANNED (r1-r3: bit-identical wrong output across
// three sync protocols AND a physical-XCD role remap -> deterministic
// math-path fault in that component).
//
// SYNC: single-writer monotone flags at the LLC (replaces r0's 3-writer
// atomic-RMW column counters). Per iteration s (t = s - l):
//   [wait]  s>0: own-layer F[nt'] >= s (lanes 0-15), lower-layer F[nt'] >= s
//           (lanes 16-31, l>=1), upper-layer A[nt'] >= s (lanes 32-47, l<=1).
//   [loads] A-fragments from hb (LLC-direct), drain, barrier, tid0 posts
//           A := s+1  (iteration-s loads are in registers).
//   [compute] MFMA from LDS + cell update; h stores LLC-direct.
//   [end]   drain, barrier, tid0 posts F := s+1.
// Ledger: own-plane RAW (pp, written s-1)        <- own-F >= s
//         input RAW (lower plane pt, written s-1)<- lower-F >= s
//         same-layer WAR (their reads @s-1)      <- own-F >= s
//         upper WAR (their reads @s-1)           <- upper-A >= s
//         WAW: disjoint slices. Base s=0: no wait, planes zeroed.
// All targets reference strictly-earlier completed events -> deadlock-free.
//
// r4 addition: bounded-poll WATCHDOG (20k polls ~ 6ms per wait, >=3 orders
// of magnitude above any legitimate wait). If the protocol were non-live on
// HW, the kernel completes with wrong data (finite absmax -> signal) instead
// of hanging the GPU and killing the container. Never trips on the
// expected path; costs 2 scalar ops per poll iteration.
// =====================================================================
__global__ void lstm_coop(
    const float* __restrict__ tracks,
    const float* __restrict__ wih0,
    const float* __restrict__ bih0, const float* __restrict__ bhh0,
    const float* __restrict__ bih1, const float* __restrict__ bhh1,
    const float* __restrict__ bih2, const float* __restrict__ bhh2,
    const unsigned short* __restrict__ wre_hi, const unsigned short* __restrict__ wre_lo,
    char* __restrict__ wsb)
{
  extern __shared__ __align__(16) unsigned short smem[];   // [mat][plane][64][WROW]

  const int tid  = threadIdx.x;
  const int l    = blockIdx.x >> 6;
  const int r6   = blockIdx.x & 63;
  const int nt   = r6 & 15, bt = r6 >> 4;
  const int b0   = bt * 64, n0 = nt * 16;
  const int w    = tid >> 6, lane = tid & 63;
  const int m    = lane & 15, q = lane >> 4;

  unsigned short* hb = (unsigned short*)(wsb + HB_OFF);

  // ---- flag pointers ----
  unsigned* FAb = (unsigned*)(wsb + FA_OFF) + bt*(3*16*64);
  unsigned* FFb = (unsigned*)(wsb + FF_OFF) + bt*(3*16*64);
  unsigned* myA = FAb + (l*16 + nt)*64;
  unsigned* myF = FFb + (l*16 + nt)*64;
  const unsigned* pollp = nullptr;            // per-lane (wave 0) poll target
  if (tid < 16)                                pollp = FFb + (l*16 + tid)*64;
  else if (tid < 32 && l >= 1)                 pollp = FFb + ((l-1)*16 + (tid-16))*64;
  else if (tid >= 32 && tid < 48 && l <= 1)    pollp = FAb + ((l+1)*16 + (tid-32))*64;

  // ---- stage this layer's weight slices into LDS (once) — exact r0 ----
  const int nmats = (l == 0) ? 1 : 2;
  const int gmat0 = (l == 0) ? 0 : (l == 1 ? 1 : 3);
  for (int mi = 0; mi < nmats; ++mi){
    const unsigned short* sh = wre_hi + (gmat0 + mi)*262144 + nt*16384;
    const unsigned short* sl = wre_lo + (gmat0 + mi)*262144 + nt*16384;
    unsigned short* dh = smem + (mi*2 + 0)*64*WROW;
    unsigned short* dl = smem + (mi*2 + 1)*64*WROW;
    for (int c = tid; c < 2048; c += 256){
      int r = c >> 5, off = (c & 31) * 8;
      *(uint4*)(dh + r*WROW + off) = *(const uint4*)(sh + r*256 + off);
      *(uint4*)(dl + r*WROW + off) = *(const uint4*)(sl + r*256 + off);
    }
  }
  __syncthreads();

  // ---- per-lane persistent state — exact r0 ----
  const float* bihL = (l==0) ? bih0 : (l==1) ? bih1 : bih2;
  const float* bhhL = (l==0) ? bhh0 : (l==1) ? bhh1 : bhh2;
  float bsum[4], wx[4][2];
  #pragma unroll
  for (int g = 0; g < 4; ++g){
    int row = g*256 + n0 + m;
    bsum[g] = bihL[row] + bhhL[row];
    wx[g][0] = wih0[row*2 + 0];
    wx[g][1] = wih0[row*2 + 1];
  }
  float cst[4] = {0.f, 0.f, 0.f, 0.f};
  const int arow = b0 + 16*w + m;                  // A-fragment batch row
  const int woff = m*WROW + q*8;                   // per-lane B-frag LDS offset

  for (int s = 0; s < 514; ++s){
    const int t = s - l;
    const bool active = (t >= 0) && (t < 512);

    // ---- x prefetch (read-only, no hazard) before the wait ----
    float xv0[4], xv1[4];
    if (l == 0 && active){
      #pragma unroll
      for (int r = 0; r < 4; ++r){
        const float* px = tracks + (b0 + 16*w + q*4 + r)*1024 + t*2;
        xv0[r] = px[0]; xv1[r] = px[1];
      }
    }

    // ---- wait: per-lane divergent poll until flag >= s (watchdog-bounded) ----
    if (s > 0){
      if (tid < 64 && pollp != nullptr){
        const unsigned tgt = (unsigned)s;
        int guard = 0;
        while (poll_llc(pollp) < tgt){
          __builtin_amdgcn_s_sleep(1);
          if (++guard > 20000) break;            // liveness watchdog
        }
      }
      __syncthreads();
    }

    // ---- A-fragment loads (LLC-direct; control-dependent on the wait) ----
    i32x4 ar_raw[8], ai_raw[8];
    int pt = 0;
    if (active){
      pt = t & 1;
      const int pp = pt ^ 1;
      const unsigned short* prec = hb + ((pp*3 + l)*256 + arow)*256 + q*8;
      #pragma unroll
      for (int ks = 0; ks < 8; ++ks)
        ar_raw[ks] = llc_load_b128(prec + ks*32);
      if (l >= 1){
        const unsigned short* pin = hb + ((pt*3 + (l-1))*256 + arow)*256 + q*8;
        #pragma unroll
        for (int ks = 0; ks < 8; ++ks)
          ai_raw[ks] = llc_load_b128(pin + ks*32);
      }
      wait_vm0();
      __builtin_amdgcn_sched_barrier(0);
    }
    // all waves' loads in registers -> post the A ack (WAR release for upper)
    __syncthreads();
    if (tid == 0) llc_store_u32(myA, (unsigned)(s + 1));

    if (active){
      // ---- MFMA: acc[g] over K=256, W split hi/lo — exact r0 ----
      f32x4 acc[4];
      #pragma unroll
      for (int g = 0; g < 4; ++g) acc[g] = (f32x4){0.f,0.f,0.f,0.f};

      { // recurrent mat: slot (l==0 ? 0 : 1)
        const unsigned short* bh = smem + ((l==0?0:2) + 0)*64*WROW + woff;
        const unsigned short* bl = smem + ((l==0?0:2) + 1)*64*WROW + woff;
        #pragma unroll
        for (int ks = 0; ks < 8; ++ks){
          bfrag8 a = __builtin_bit_cast(bfrag8, ar_raw[ks]);
          #pragma unroll
          for (int g = 0; g < 4; ++g){
            bfrag8 fh = *(const bfrag8*)(bh + g*16*WROW + ks*32);
            bfrag8 fl = *(const bfrag8*)(bl + g*16*WROW + ks*32);
            acc[g] = __builtin_amdgcn_mfma_f32_16x16x32_bf16(a, fh, acc[g], 0, 0, 0);
            acc[g] = __builtin_amdgcn_mfma_f32_16x16x32_bf16(a, fl, acc[g], 0, 0, 0);
          }
        }
      }
      if (l >= 1){ // input mat: slot 0
        const unsigned short* bh = smem + 0*64*WROW + woff;
        const unsigned short* bl = smem + 1*64*WROW + woff;
        #pragma unroll
        for (int ks = 0; ks < 8; ++ks){
          bfrag8 a = __builtin_bit_cast(bfrag8, ai_raw[ks]);
          #pragma unroll
          for (int g = 0; g < 4; ++g){
            bfrag8 fh = *(const bfrag8*)(bh + g*16*WROW + ks*32);
            bfrag8 fl = *(const bfrag8*)(bl + g*16*WROW + ks*32);
            acc[g] = __builtin_amdgcn_mfma_f32_16x16x32_bf16(a, fh, acc[g], 0, 0, 0);
            acc[g] = __builtin_amdgcn_mfma_f32_16x16x32_bf16(a, fl, acc[g], 0, 0, 0);
          }
        }
      }

      // ---- cell update (gates in registers; c exact fp32); h stores LLC ----
      unsigned short* hout = hb + ((pt*3 + l)*256 + 0)*256;
      #pragma unroll
      for (int r = 0; r < 4; ++r){
        float xi = 0.f, xf = 0.f, xg = 0.f, xo = 0.f;
        if (l == 0){
          xi = xv0[r]*wx[0][0] + xv1[r]*wx[0][1];
          xf = xv0[r]*wx[1][0] + xv1[r]*wx[1][1];
          xg = xv0[r]*wx[2][0] + xv1[r]*wx[2][1];
          xo = xv0[r]*wx[3][0] + xv1[r]*wx[3][1];
        }
        float gi = acc[0][r] + bsum[0] + xi;
        float gf = acc[1][r] + bsum[1] + xf;
        float gg = acc[2][r] + bsum[2] + xg;
        float go = acc[3][r] + bsum[3] + xo;
        float iv = sigf(gi);
        float fv = sigf(gf);
        float gv = tanh_fast(gg);
        float ov = sigf(go);
        cst[r] = fv * cst[r] + iv * gv;
        float hv = ov * tanh_fast(cst[r]);
        llc_store_b16(&hout[(b0 + 16*w + q*4 + r)*256 + n0 + m], f2bf(hv));
      }
    }

    // ---- arrive: drain own stores, block barrier, post F (fire-and-forget) ----
    wait_vm0();
    __builtin_amdgcn_sched_barrier(0);
    __syncthreads();
    if (tid == 0) llc_store_u32(myF, (unsigned)(s + 1));
  }
}

// out[b] = elu(h2_final[b]) @ W_pred^T + b_pred ; h2 final parity = 511&1 = 1 -> plane 5
__global__ void head_kernel(const unsigned short* __restrict__ hb,
                            const float* __restrict__ wpred,
                            const float* __restrict__ bpred,
                            float* __restrict__ out){
  const int b = blockIdx.x;
  const int k = threadIdx.x;
  const int idx = (5*256 + b)*256 + k;
  float h = bf2f(hb[idx]);
  float e = (h > 0.f) ? h : expm1f(h);
  float v0 = e * wpred[k];
  float v1 = e * wpred[256 + k];
  #pragma unroll
  for (int off = 32; off > 0; off >>= 1){
    v0 += __shfl_down(v0, off, 64);
    v1 += __shfl_down(v1, off, 64);
  }
  __shared__ float r0[4], r1[4];
  int wv = threadIdx.x >> 6, ln = threadIdx.x & 63;
  if (ln == 0){ r0[wv] = v0; r1[wv] = v1; }
  __syncthreads();
  if (threadIdx.x == 0){
    out[b*2 + 0] = r0[0] + r0[1] + r0[2] + r0[3] + bpred[0];
    out[b*2 + 1] = r1[0] + r1[1] + r1[2] + r1[3] + bpred[1];
  }
}

extern "C" void kernel_launch(void* const* d_in, const int* in_sizes, int n_in,
                              void* d_out, int out_size, void* d_ws, size_t ws_size,
                              hipStream_t stream) {
  const float* tracks = (const float*)d_in[0];
  const float* wih0   = (const float*)d_in[1];
  const float* whh0   = (const float*)d_in[2];
  const float* bih0   = (const float*)d_in[3];
  const float* bhh0   = (const float*)d_in[4];
  const float* wih1   = (const float*)d_in[5];
  const float* whh1   = (const float*)d_in[6];
  const float* bih1   = (const float*)d_in[7];
  const float* bhh1   = (const float*)d_in[8];
  const float* wih2   = (const float*)d_in[9];
  const float* whh2   = (const float*)d_in[10];
  const float* bih2   = (const float*)d_in[11];
  const float* bhh2   = (const float*)d_in[12];
  const float* wpred  = (const float*)d_in[13];
  const float* bpred  = (const float*)d_in[14];
  float* out = (float*)d_out;

  char* wsb = (char*)d_ws;
  unsigned short* wre_hi = (unsigned short*)(wsb);
  unsigned short* wre_lo = (unsigned short*)(wsb + WRE_LO_OFF);
  const unsigned short* hb = (const unsigned short*)(wsb + HB_OFF);

  (void)hipFuncSetAttribute((const void*)lstm_coop,
                            hipFuncAttributeMaxDynamicSharedMemorySize, SMEM_BYTES);

  init_reorder<<<5120, 256, 0, stream>>>(whh0, wih1, whh1, wih2, whh2, wre_hi, wre_lo);
  // zero hb + FA + FF: (WS_END - HB_OFF)/16 = 55296 uint4
  init_zero<<<216, 256, 0, stream>>>((uint4*)(wsb + HB_OFF), 55296);

  void* args[11];
  args[0]  = (void*)&tracks;
  args[1]  = (void*)&wih0;
  args[2]  = (void*)&bih0;
  args[3]  = (void*)&bhh0;
  args[4]  = (void*)&bih1;
  args[5]  = (void*)&bhh1;
  args[6]  = (void*)&bih2;
  args[7]  = (void*)&bhh2;
  args[8]  = (void*)&wre_hi;
  args[9]  = (void*)&wre_lo;
  args[10] = (void*)&wsb;
  // cooperative launch kept purely for the all-blocks-co-resident guarantee
  hipLaunchCooperativeKernel((const void*)lstm_coop, dim3(192), dim3(256), args,
                             SMEM_BYTES, stream);

  head_kernel<<<256, 256, 0, stream>>>(hb, wpred, bpred, out);
}

// Round 7
// 3693.399 us; speedup vs baseline: 1.0934x; 1.0934x over previous
//
#include <hip/hip_runtime.h>
#include <math.h>

typedef __attribute__((ext_vector_type(4))) float f32x4;
typedef __attribute__((ext_vector_type(4))) int   i32x4;
typedef __attribute__((ext_vector_type(8))) short bfrag8;   // 8 bf16 = 4 VGPRs

// ---- ws layout (bytes) ----
// wre_hi: 5 mats * 1024 * 256 * 2B = 2621440 @ 0
// wre_lo: same                              @ 2621440
#define WRE_LO_OFF 2621440
// h rings (ALL LLC domain — L2-scope comms are BANNED after r6):
//   ring_l0: [bt(4)][slot(4)][64][256] bf16 = 524288 B
//   ring_l1: [bt(4)][slot(4)][64][256] bf16 = 524288 B
//   ring_l2: [bt(4)][slot(2)][64][256] bf16 = 262144 B
#define RING0_OFF  5242880
#define RING1_OFF  5767168
#define RING2_OFF  6291456
// flags F[l][bt][nt]: single-writer monotone (= t+1 after step t), 256B padded
#define FLG_OFF    6553600   // 3*4*16*256 = 49152 B
#define WS_END     6602752

// dynamic LDS: [2 mats][2 planes][64][WROW] = 135168 B (exact r0 math path)
#define WROW 264
#define SMEM_BYTES (4 * 64 * WROW * 2)

__device__ __forceinline__ unsigned short f2bf(float f){
  union { float f; unsigned u; } x; x.f = f;
  unsigned r = x.u + 0x7FFFu + ((x.u >> 16) & 1u);   // RNE
  return (unsigned short)(r >> 16);
}
__device__ __forceinline__ float bf2f(unsigned short s){
  union { unsigned u; float f; } x; x.u = ((unsigned)s) << 16; return x.f;
}
__device__ __forceinline__ float sigf(float x){
  return 1.0f / (1.0f + __expf(-x));
}
__device__ __forceinline__ float tanh_fast(float x){
  x = fminf(fmaxf(x, -15.0f), 15.0f);
  float e = __expf(2.0f * x);
  return (e - 1.0f) / (e + 1.0f);
}

// ---- LLC-direct (device coherence point): sc0 sc1 bypasses L1 and L2.
// The ONLY cross-block scope used anywhere (r0/r5-proven).
__device__ __forceinline__ i32x4 llc_load_b128(const void* p){
  i32x4 r;
  asm volatile("global_load_dwordx4 %0, %1, off sc0 sc1"
               : "=v"(r) : "v"(p) : "memory");
  return r;
}
__device__ __forceinline__ void llc_store_b16(void* p, unsigned short v){
  unsigned int vv = v;
  asm volatile("global_store_short %0, %1, off sc0 sc1"
               : : "v"(p), "v"(vv) : "memory");
}
__device__ __forceinline__ void llc_store_u32(void* p, unsigned v){
  asm volatile("global_store_dword %0, %1, off sc0 sc1"
               : : "v"(p), "v"(v) : "memory");
}
__device__ __forceinline__ unsigned poll_llc(const unsigned int* p){
  unsigned r;
  asm volatile("global_load_dword %0, %1, off sc0 sc1\n\ts_waitcnt vmcnt(0)"
               : "=v"(r) : "v"(p) : "memory");
  return r;
}
__device__ __forceinline__ void wait_vm0(){
  asm volatile("s_waitcnt vmcnt(0)" ::: "memory");
}

// Reorder the 5 big weight mats into per-(nt)-contiguous rows, split bf16 hi/lo.
// dest row d in [0,1024): nt=d>>6, g=(d>>4)&3, n=d&15 ; src row = g*256 + nt*16 + n
__global__ void init_reorder(const float* __restrict__ hh0, const float* __restrict__ ih1,
                             const float* __restrict__ hh1, const float* __restrict__ ih2,
                             const float* __restrict__ hh2,
                             unsigned short* __restrict__ wre_hi,
                             unsigned short* __restrict__ wre_lo){
  int e = blockIdx.x * 256 + threadIdx.x;        // 5*2^18 total
  int mat = e >> 18;
  int d   = (e >> 8) & 1023;
  int k   = e & 255;
  int nt = d >> 6, g = (d >> 4) & 3, n = d & 15;
  int src_row = g*256 + nt*16 + n;
  const float* W = (mat==0) ? hh0 : (mat==1) ? ih1 : (mat==2) ? hh1 : (mat==3) ? ih2 : hh2;
  float v = W[src_row*256 + k];
  unsigned short hi = f2bf(v);
  float lo = v - bf2f(hi);
  wre_hi[e] = hi;
  wre_lo[e] = f2bf(lo);
}

__global__ void init_zero(uint4* __restrict__ p, int n16){
  int i = blockIdx.x * 256 + threadIdx.x;
  if (i < n16) p[i] = make_uint4(0u,0u,0u,0u);
}

// =====================================================================
// DECOUPLED layer-pipelined LSTM — all-LLC, per-layer step cadence.
// 192 blocks = layer(3) x nt(16) x bt(4); 256 threads. Exact r0 math
// (LDS hi/lo weights; register-weights BANNED r1-r3; L2-scope BANNED r6).
//
// Each layer l runs its OWN loop t = 0..511 writing h_l(t) into an LLC
// ring: l0,l1 depth 4 (slot t&3), l2 depth 2 (slot t&1). Layer l>=1 input
// x(t) = h_{l-1}(t) read from the lower ring (slot t&3).
//
// Flags: F[l][bt][nt] := t+1 posted by tid0 after step t (single-writer
// monotone, sc0sc1 store — r5-proven primitive). Waits before step t:
//  * own column  F_l[bt][*]  >= t    (peers finished t-1; covers own-ring
//    RAW of h_l(t-1) and own-ring WAR: slot t&m holds h_l(t-D), peers read
//    it at their step t-D+1 <= t-1. Tight, irreducible 16-way all-gather.)
//  * lower col   F_{l-1}[bt][*] >= t+1  (l>=1; h_{l-1}(t) at LLC. Producer
//    runs AHEAD in steady state -> pre-satisfied, off critical path.)
//  * upper col   F_{l+1}[bt][*] >= t-3  (l<=1, t>=4; upper read h_l(t-4)
//    during its step t-4, so slot t&3 is reusable. 3 steps of slack.)
// Base t=0: rings zeroed, own/upper waits vacuous, lower = F>=1.
// No cycle at equal indices (lower-wait producer never waits on consumer
// at >= its own index) -> deadlock-free. Watchdog (20k polls) converts
// any protocol surprise into finite-wrong-answer, never a container kill.
//
// Critical path per step (steady state): observe own column (~1 LLC RTT)
// -> A loads (~1 RTT) -> MFMA/LDS (~2.5-3k cy) -> drain -> F post.
// vs r0/r5's 3-layer lockstep chain. Predicted ~2x faster.
// =====================================================================
__global__ void lstm_coop(
    const float* __restrict__ tracks,
    const float* __restrict__ wih0,
    const float* __restrict__ bih0, const float* __restrict__ bhh0,
    const float* __restrict__ bih1, const float* __restrict__ bhh1,
    const float* __restrict__ bih2, const float* __restrict__ bhh2,
    const unsigned short* __restrict__ wre_hi, const unsigned short* __restrict__ wre_lo,
    char* __restrict__ wsb)
{
  extern __shared__ __align__(16) unsigned short smem[];   // [mat][plane][64][WROW]

  const int tid  = threadIdx.x;
  const int l    = blockIdx.x >> 6;
  const int r6   = blockIdx.x & 63;
  const int nt   = r6 & 15, bt = r6 >> 4;
  const int b0   = bt * 64, n0 = nt * 16;
  const int w    = tid >> 6, lane = tid & 63;
  const int m    = lane & 15, q = lane >> 4;

  // ---- ring pointers (shorts). own ring + lower ring ----
  const int Dm   = (l == 2) ? 1 : 3;            // own slot mask (depth-1)
  unsigned short* ring_own =
      (unsigned short*)(wsb + ((l==0) ? RING0_OFF : (l==1) ? RING1_OFF : RING2_OFF))
      + bt * ((l==2) ? 2 : 4) * 16384;
  unsigned short* ring_low = (l == 0) ? nullptr :
      (unsigned short*)(wsb + ((l==1) ? RING0_OFF : RING1_OFF)) + bt * 4 * 16384;

  // ---- flag pointers ----
  unsigned* FL  = (unsigned*)(wsb + FLG_OFF);
  unsigned* myF = FL + ((l*4 + bt)*16 + nt)*64;
  // per-lane poll target pointer + class
  const unsigned* pollp = nullptr; int pcls = 0;  // 1=own 2=lower 3=upper
  if (tid < 16){                         pollp = FL + ((l*4 + bt)*16 + tid)*64;       pcls = 1; }
  else if (tid < 32 && l >= 1){          pollp = FL + (((l-1)*4 + bt)*16 + (tid-16))*64; pcls = 2; }
  else if (tid >= 32 && tid < 48 && l <= 1){ pollp = FL + (((l+1)*4 + bt)*16 + (tid-32))*64; pcls = 3; }

  // ---- stage this layer's weight slices into LDS (once) — exact r0 ----
  const int nmats = (l == 0) ? 1 : 2;
  const int gmat0 = (l == 0) ? 0 : (l == 1 ? 1 : 3);
  for (int mi = 0; mi < nmats; ++mi){
    const unsigned short* sh = wre_hi + (gmat0 + mi)*262144 + nt*16384;
    const unsigned short* sl = wre_lo + (gmat0 + mi)*262144 + nt*16384;
    unsigned short* dh = smem + (mi*2 + 0)*64*WROW;
    unsigned short* dl = smem + (mi*2 + 1)*64*WROW;
    for (int c = tid; c < 2048; c += 256){
      int r = c >> 5, off = (c & 31) * 8;
      *(uint4*)(dh + r*WROW + off) = *(const uint4*)(sh + r*256 + off);
      *(uint4*)(dl + r*WROW + off) = *(const uint4*)(sl + r*256 + off);
    }
  }
  __syncthreads();

  // ---- per-lane persistent state — exact r0 ----
  const float* bihL = (l==0) ? bih0 : (l==1) ? bih1 : bih2;
  const float* bhhL = (l==0) ? bhh0 : (l==1) ? bhh1 : bhh2;
  float bsum[4], wx[4][2];
  #pragma unroll
  for (int g = 0; g < 4; ++g){
    int row = g*256 + n0 + m;
    bsum[g] = bihL[row] + bhhL[row];
    wx[g][0] = wih0[row*2 + 0];
    wx[g][1] = wih0[row*2 + 1];
  }
  float cst[4] = {0.f, 0.f, 0.f, 0.f};
  const int lrow = 16*w + m;                       // local batch row (A frag)
  const int woff = m*WROW + q*8;                   // B-frag LDS offset

  for (int t = 0; t < 512; ++t){
    // ---- x prefetch (l0, read-only) before the wait ----
    float xv0[4], xv1[4];
    if (l == 0){
      #pragma unroll
      for (int r = 0; r < 4; ++r){
        const float* px = tracks + (b0 + 16*w + q*4 + r)*1024 + t*2;
        xv0[r] = px[0]; xv1[r] = px[1];
      }
    }

    // ---- wait: per-lane poll until target (watchdog-bounded) ----
    {
      unsigned tgt = 0;
      if      (pcls == 1) tgt = (unsigned)t;                       // own col
      else if (pcls == 2) tgt = (unsigned)(t + 1);                 // lower col
      else if (pcls == 3) tgt = (t >= 4) ? (unsigned)(t - 3) : 0u; // upper col
      if (tgt){
        int guard = 0;
        while (poll_llc(pollp) < tgt){
          __builtin_amdgcn_s_sleep(1);
          if (++guard > 20000) break;            // liveness watchdog
        }
      }
      __syncthreads();
    }

    // ---- A-fragment loads (LLC-direct; control-dependent on the wait) ----
    i32x4 ar_raw[8], ai_raw[8];
    {
      const unsigned short* prec = ring_own + ((t-1) & Dm)*16384 + lrow*256 + q*8;
      if (t == 0) prec = ring_own + Dm*16384 + lrow*256 + q*8;     // zeroed slot
      #pragma unroll
      for (int ks = 0; ks < 8; ++ks)
        ar_raw[ks] = llc_load_b128(prec + ks*32);
      if (l >= 1){
        const unsigned short* pin = ring_low + (t & 3)*16384 + lrow*256 + q*8;
        #pragma unroll
        for (int ks = 0; ks < 8; ++ks)
          ai_raw[ks] = llc_load_b128(pin + ks*32);
      }
    }
    wait_vm0();
    __builtin_amdgcn_sched_barrier(0);

    // ---- MFMA: acc[g] over K=256, W split hi/lo — exact r0 ----
    f32x4 acc[4];
    #pragma unroll
    for (int g = 0; g < 4; ++g) acc[g] = (f32x4){0.f,0.f,0.f,0.f};

    { // recurrent mat: slot (l==0 ? 0 : 1)
      const unsigned short* bh = smem + ((l==0?0:2) + 0)*64*WROW + woff;
      const unsigned short* bl = smem + ((l==0?0:2) + 1)*64*WROW + woff;
      #pragma unroll
      for (int ks = 0; ks < 8; ++ks){
        bfrag8 a = __builtin_bit_cast(bfrag8, ar_raw[ks]);
        #pragma unroll
        for (int g = 0; g < 4; ++g){
          bfrag8 fh = *(const bfrag8*)(bh + g*16*WROW + ks*32);
          bfrag8 fl = *(const bfrag8*)(bl + g*16*WROW + ks*32);
          acc[g] = __builtin_amdgcn_mfma_f32_16x16x32_bf16(a, fh, acc[g], 0, 0, 0);
          acc[g] = __builtin_amdgcn_mfma_f32_16x16x32_bf16(a, fl, acc[g], 0, 0, 0);
        }
      }
    }
    if (l >= 1){ // input mat: slot 0
      const unsigned short* bh = smem + 0*64*WROW + woff;
      const unsigned short* bl = smem + 1*64*WROW + woff;
      #pragma unroll
      for (int ks = 0; ks < 8; ++ks){
        bfrag8 a = __builtin_bit_cast(bfrag8, ai_raw[ks]);
        #pragma unroll
        for (int g = 0; g < 4; ++g){
          bfrag8 fh = *(const bfrag8*)(bh + g*16*WROW + ks*32);
          bfrag8 fl = *(const bfrag8*)(bl + g*16*WROW + ks*32);
          acc[g] = __builtin_amdgcn_mfma_f32_16x16x32_bf16(a, fh, acc[g], 0, 0, 0);
          acc[g] = __builtin_amdgcn_mfma_f32_16x16x32_bf16(a, fl, acc[g], 0, 0, 0);
        }
      }
    }

    // ---- cell update (exact r0); h stores to own ring slot t (LLC) ----
    unsigned short* hout = ring_own + (t & Dm)*16384;
    #pragma unroll
    for (int r = 0; r < 4; ++r){
      float xi = 0.f, xf = 0.f, xg = 0.f, xo = 0.f;
      if (l == 0){
        xi = xv0[r]*wx[0][0] + xv1[r]*wx[0][1];
        xf = xv0[r]*wx[1][0] + xv1[r]*wx[1][1];
        xg = xv0[r]*wx[2][0] + xv1[r]*wx[2][1];
        xo = xv0[r]*wx[3][0] + xv1[r]*wx[3][1];
      }
      float gi = acc[0][r] + bsum[0] + xi;
      float gf = acc[1][r] + bsum[1] + xf;
      float gg = acc[2][r] + bsum[2] + xg;
      float go = acc[3][r] + bsum[3] + xo;
      float iv = sigf(gi);
      float fv = sigf(gf);
      float gv = tanh_fast(gg);
      float ov = sigf(go);
      cst[r] = fv * cst[r] + iv * gv;
      float hv = ov * tanh_fast(cst[r]);
      llc_store_b16(&hout[(16*w + q*4 + r)*256 + n0 + m], f2bf(hv));
    }

    // ---- arrive: drain stores, block barrier, post F := t+1 ----
    wait_vm0();
    __builtin_amdgcn_sched_barrier(0);
    __syncthreads();
    if (tid == 0) llc_store_u32(myF, (unsigned)(t + 1));
  }
}

// out[b] = elu(h2_final[b]) @ W_pred^T + b_pred ; h2(511) in ring_l2 slot 511&1=1
__global__ void head_kernel(const char* __restrict__ wsb,
                            const float* __restrict__ wpred,
                            const float* __restrict__ bpred,
                            float* __restrict__ out){
  const int b = blockIdx.x;
  const int k = threadIdx.x;
  const int bt = b >> 6, row = b & 63;
  const unsigned short* ring2 = (const unsigned short*)(wsb + RING2_OFF);
  float h = bf2f(ring2[(bt*2 + 1)*16384 + row*256 + k]);
  float e = (h > 0.f) ? h : expm1f(h);
  float v0 = e * wpred[k];
  float v1 = e * wpred[256 + k];
  #pragma unroll
  for (int off = 32; off > 0; off >>= 1){
    v0 += __shfl_down(v0, off, 64);
    v1 += __shfl_down(v1, off, 64);
  }
  __shared__ float r0[4], r1[4];
  int wv = threadIdx.x >> 6, ln = threadIdx.x & 63;
  if (ln == 0){ r0[wv] = v0; r1[wv] = v1; }
  __syncthreads();
  if (threadIdx.x == 0){
    out[b*2 + 0] = r0[0] + r0[1] + r0[2] + r0[3] + bpred[0];
    out[b*2 + 1] = r1[0] + r1[1] + r1[2] + r1[3] + bpred[1];
  }
}

extern "C" void kernel_launch(void* const* d_in, const int* in_sizes, int n_in,
                              void* d_out, int out_size, void* d_ws, size_t ws_size,
                              hipStream_t stream) {
  const float* tracks = (const float*)d_in[0];
  const float* wih0   = (const float*)d_in[1];
  const float* whh0   = (const float*)d_in[2];
  const float* bih0   = (const float*)d_in[3];
  const float* bhh0   = (const float*)d_in[4];
  const float* wih1   = (const float*)d_in[5];
  const float* whh1   = (const float*)d_in[6];
  const float* bih1   = (const float*)d_in[7];
  const float* bhh1   = (const float*)d_in[8];
  const float* wih2   = (const float*)d_in[9];
  const float* whh2   = (const float*)d_in[10];
  const float* bih2   = (const float*)d_in[11];
  const float* bhh2   = (const float*)d_in[12];
  const float* wpred  = (const float*)d_in[13];
  const float* bpred  = (const float*)d_in[14];
  float* out = (float*)d_out;

  char* wsb = (char*)d_ws;
  unsigned short* wre_hi = (unsigned short*)(wsb);
  unsigned short* wre_lo = (unsigned short*)(wsb + WRE_LO_OFF);

  (void)hipFuncSetAttribute((const void*)lstm_coop,
                            hipFuncAttributeMaxDynamicSharedMemorySize, SMEM_BYTES);

  init_reorder<<<5120, 256, 0, stream>>>(whh0, wih1, whh1, wih2, whh2, wre_hi, wre_lo);
  // zero rings + flags: (WS_END - RING0_OFF)/16 = 84992 uint4
  init_zero<<<332, 256, 0, stream>>>((uint4*)(wsb + RING0_OFF), 84992);

  void* args[11];
  args[0]  = (void*)&tracks;
  args[1]  = (void*)&wih0;
  args[2]  = (void*)&bih0;
  args[3]  = (void*)&bhh0;
  args[4]  = (void*)&bih1;
  args[5]  = (void*)&bhh1;
  args[6]  = (void*)&bih2;
  args[7]  = (void*)&bhh2;
  args[8]  = (void*)&wre_hi;
  args[9]  = (void*)&wre_lo;
  args[10] = (void*)&wsb;
  // cooperative launch kept purely for the all-blocks-co-resident guarantee
  hipLaunchCooperativeKernel((const void*)lstm_coop, dim3(192), dim3(256), args,
                             SMEM_BYTES, stream);

  head_kernel<<<256, 256, 0, stream>>>(wsb, wpred, bpred, out);
}